// Round 4
// baseline (153.512 us; speedup 1.0000x reference)
//
#include <hip/hip_runtime.h>
#include <hip/hip_bf16.h>

// Problem: B=2, L=2048, D=1024, N=16  -> rows R = 4096, K = 1024
// y[r,d] = x[r,d] * softplus((x@W1^T)[r,d] + b1[d]) * s[r]
// s[r]   = sum_n (x@W2^T + b2)[r,n] * (x@W3^T + b3)[r,n]
// (dA * h0 == 0, so A is unused.)

#define ROWS 4096
#define KDIM 1024
// GEMM tile: 128x64, BK=32 -> 512 blocks, XCD-swizzled
#define BM 128
#define BN 64
#define BK 32

typedef __attribute__((ext_vector_type(8))) __bf16 bf16x8;
typedef __attribute__((ext_vector_type(4))) float f32x4;

// ---------- helpers ----------
__device__ __forceinline__ unsigned short f2bf_rne(float f) {
    unsigned u = __float_as_uint(f);
    u += 0x7FFFu + ((u >> 16) & 1u);   // round-to-nearest-even
    return (unsigned short)(u >> 16);
}
__device__ __forceinline__ unsigned pack2(float lo, float hi) {
    return (unsigned)f2bf_rne(lo) | ((unsigned)f2bf_rne(hi) << 16);
}
__device__ __forceinline__ bf16x8 cvt8(float4 a, float4 b) {
    union { uint4 u; bf16x8 h; } o;
    o.u.x = pack2(a.x, a.y); o.u.y = pack2(a.z, a.w);
    o.u.z = pack2(b.x, b.y); o.u.w = pack2(b.z, b.w);
    return o.h;
}
__device__ __forceinline__ void async16(const void* g, void* l) {
    __builtin_amdgcn_global_load_lds(
        (const __attribute__((address_space(1))) void*)g,
        (__attribute__((address_space(3))) void*)l, 16, 0, 0);
}

// ---------- kernel 1: convert (x,W1 -> bf16) + s[r] via MFMA tail blocks ----------
// blocks [0,2560): pure streaming fp32->bf16 of x then W1 (8 elems/thread).
// blocks [2560,2624): s-blocks. Each wave: 16 rows; 32 k-steps; per step load
//   x/W2/W3 fp32 (32 B/lane, contiguous), convert to bf16 frags in-register,
//   2 MFMA (B and C accumulators). W2/W3 loads are identical across all 64
//   blocks -> L2-hot. Epilogue: p=(B+b2)(C+b3), shuffle-reduce over n, store s.
__global__ __launch_bounds__(256) void prep_kernel(
        const float* __restrict__ x,  const float* __restrict__ W1,
        const float* __restrict__ W2, const float* __restrict__ b2,
        const float* __restrict__ W3, const float* __restrict__ b3,
        unsigned short* __restrict__ xb, unsigned short* __restrict__ w1b,
        float* __restrict__ s) {
    const int bid = blockIdx.x;
    if (bid < 2560) {
        const long long NX = (long long)ROWS * KDIM;        // 4,194,304
        long long i = ((long long)bid * 256 + threadIdx.x) * 8;
        const float* src;
        unsigned short* dst;
        if (i < NX) { src = x + i;         dst = xb + i; }
        else        { src = W1 + (i - NX); dst = w1b + (i - NX); }
        float4 a = *(const float4*)src;
        float4 b = *(const float4*)(src + 4);
        uint4 o;
        o.x = pack2(a.x, a.y); o.y = pack2(a.z, a.w);
        o.z = pack2(b.x, b.y); o.w = pack2(b.z, b.w);
        *(uint4*)dst = o;
        return;
    }
    // ---- s path ----
    const int sb = bid - 2560;            // 0..63
    const int t = threadIdx.x;
    const int lane = t & 63;
    const int wv = t >> 6;
    const int m = lane & 15;              // row-within-16 (A) / n index (B)
    const int kq = (lane >> 4) * 8;       // k quad offset
    const int r0 = sb * 64 + wv * 16;     // wave's 16 rows

    f32x4 accB = (f32x4){0.f, 0.f, 0.f, 0.f};
    f32x4 accC = (f32x4){0.f, 0.f, 0.f, 0.f};
    const float* xr  = x  + (size_t)(r0 + m) * KDIM + kq;
    const float* w2r = W2 + (size_t)m * KDIM + kq;
    const float* w3r = W3 + (size_t)m * KDIM + kq;
#pragma unroll 4
    for (int k0 = 0; k0 < KDIM; k0 += 32) {
        float4 xa  = *(const float4*)(xr + k0);
        float4 xbv = *(const float4*)(xr + k0 + 4);
        float4 w2a = *(const float4*)(w2r + k0);
        float4 w2b = *(const float4*)(w2r + k0 + 4);
        float4 w3a = *(const float4*)(w3r + k0);
        float4 w3b = *(const float4*)(w3r + k0 + 4);
        bf16x8 af = cvt8(xa, xbv);
        accB = __builtin_amdgcn_mfma_f32_16x16x32_bf16(af, cvt8(w2a, w2b), accB, 0, 0, 0);
        accC = __builtin_amdgcn_mfma_f32_16x16x32_bf16(af, cvt8(w3a, w3b), accC, 0, 0, 0);
    }
    // C/D layout: lane holds D[row = (lane>>4)*4 + r][col = n = lane&15]
    const float b2n = b2[m], b3n = b3[m];
    const int q4 = (lane >> 4) * 4;
#pragma unroll
    for (int r = 0; r < 4; ++r) {
        float p = (accB[r] + b2n) * (accC[r] + b3n);
        p += __shfl_xor(p, 1, 64);
        p += __shfl_xor(p, 2, 64);
        p += __shfl_xor(p, 4, 64);
        p += __shfl_xor(p, 8, 64);
        if (m == 0) s[r0 + q4 + r] = p;
    }
}

// ---------- kernel 2: bf16 MFMA GEMM + fused epilogue, XCD-swizzled grid ----------
// 512 blocks (1-D). bid&7 = XCD; each XCD: 4 row-strips x 16 col-tiles ->
// per-XCD L2 working set = xb 1 MB + w1b 2 MB = 3 MB < 4 MB.
// 256 thr = 4 waves in 2x2; each wave: 64x32 via 4x2 mfma_f32_16x16x32_bf16.
__global__ __launch_bounds__(256) void gemm_fused(
        const unsigned short* __restrict__ xb,   // [4096][1024] bf16
        const unsigned short* __restrict__ w1b,  // [1024][1024] bf16 (row e, col k)
        const float* __restrict__ b1,
        const float* __restrict__ x,             // fp32 original
        const float* __restrict__ s,
        float* __restrict__ y) {
    __shared__ __align__(16) unsigned short As[BM * BK];  // 8 KB, [row][k]
    __shared__ __align__(16) unsigned short Bs[BN * BK];  // 4 KB, [col][k]

    const int bid = blockIdx.x;
    const int xcd = bid & 7;
    const int l = bid >> 3;                   // 0..63
    const int row0 = (xcd * 4 + (l >> 4)) * BM;
    const int col0 = (l & 15) * BN;

    const int t = threadIdx.x;
    const int lane = t & 63;
    const int wv = t >> 6;          // 0..3
    const int wm = wv >> 1;         // wave row 0..1 (64 rows each)
    const int wn = wv & 1;          // wave col 0..1 (32 cols each)

    f32x4 acc[4][2];
#pragma unroll
    for (int mi = 0; mi < 4; ++mi)
#pragma unroll
        for (int ni = 0; ni < 2; ++ni)
            acc[mi][ni] = (f32x4){0.f, 0.f, 0.f, 0.f};

    const int srow = (lane >> 2);        // 0..15 within 16-row chunk
    const int skoff = (lane & 3) * 8;    // 0,8,16,24 elements
    const int ml = lane & 15;
    const int kq = (lane >> 4) * 8;

    for (int k0 = 0; k0 < KDIM; k0 += BK) {
        __syncthreads();
        // A: 8 chunks of 16 rows; wave wv stages chunks 2wv, 2wv+1
#pragma unroll
        for (int i = 0; i < 2; ++i) {
            int c = wv * 2 + i;
            int rrow = c * 16 + srow;
            async16(xb + (size_t)(row0 + rrow) * KDIM + k0 + skoff, &As[c * 512]);
        }
        // B: 4 chunks of 16 rows; wave wv stages chunk wv
        {
            int rrow = wv * 16 + srow;
            async16(w1b + (size_t)(col0 + rrow) * KDIM + k0 + skoff, &Bs[wv * 512]);
        }
        __syncthreads();

        bf16x8 af[4], bfr[2];
#pragma unroll
        for (int i = 0; i < 4; ++i)
            af[i]  = *(const bf16x8*)&As[(wm * 64 + i * 16 + ml) * BK + kq];
#pragma unroll
        for (int i = 0; i < 2; ++i)
            bfr[i] = *(const bf16x8*)&Bs[(wn * 32 + i * 16 + ml) * BK + kq];
#pragma unroll
        for (int mi = 0; mi < 4; ++mi)
#pragma unroll
            for (int ni = 0; ni < 2; ++ni)
                acc[mi][ni] = __builtin_amdgcn_mfma_f32_16x16x32_bf16(
                    af[mi], bfr[ni], acc[mi][ni], 0, 0, 0);
    }

    // epilogue: y = softplus(acc + b1) * x * s ; D layout: col=lane&15, row=(lane>>4)*4+reg
    const int q4 = (lane >> 4) * 4;
#pragma unroll
    for (int mi = 0; mi < 4; ++mi) {
        const int rbase = row0 + wm * 64 + mi * 16 + q4;
        float4 s4 = *(const float4*)&s[rbase];
        const float* sp4 = (const float*)&s4;
#pragma unroll
        for (int ni = 0; ni < 2; ++ni) {
            const int c = col0 + wn * 32 + ni * 16 + ml;
            const float bias = b1[c];
#pragma unroll
            for (int r = 0; r < 4; ++r) {
                float z = acc[mi][ni][r] + bias;
                float sp = fmaxf(z, 0.f) + log1pf(__expf(-fabsf(z)));
                size_t idx = (size_t)(rbase + r) * KDIM + c;
                y[idx] = sp * x[idx] * sp4[r];
            }
        }
    }
}

// ---------- launch ----------
extern "C" void kernel_launch(void* const* d_in, const int* in_sizes, int n_in,
                              void* d_out, int out_size, void* d_ws, size_t ws_size,
                              hipStream_t stream) {
    const float* x  = (const float*)d_in[0];
    const float* W1 = (const float*)d_in[1];
    const float* b1 = (const float*)d_in[2];
    const float* W2 = (const float*)d_in[3];
    const float* b2 = (const float*)d_in[4];
    const float* W3 = (const float*)d_in[5];
    const float* b3 = (const float*)d_in[6];
    // d_in[7] = A : unused (multiplied by h0 == 0 in the reference)
    float* y = (float*)d_out;

    unsigned short* xb  = (unsigned short*)d_ws;            // 4096*1024 bf16 = 8 MB
    unsigned short* w1b = xb + (size_t)ROWS * KDIM;         // 1024*1024 bf16 = 2 MB
    float* s = (float*)(w1b + (size_t)KDIM * KDIM);         // 4096 f32

    prep_kernel<<<dim3(2624), dim3(256), 0, stream>>>(x, W1, W2, b2, W3, b3, xb, w1b, s);
    gemm_fused<<<dim3(512), dim3(256), 0, stream>>>(xb, w1b, b1, x, s, y);
}

// Round 5
// 121.774 us; speedup vs baseline: 1.2606x; 1.2606x over previous
//
#include <hip/hip_runtime.h>
#include <hip/hip_bf16.h>

// Problem: B=2, L=2048, D=1024, N=16  -> rows R = 4096, K = 1024
// y[r,d] = x[r,d] * softplus((x@W1^T)[r,d] + b1[d]) * s[r]
// s[r]   = sum_n (x@W2^T + b2)[r,n] * (x@W3^T + b3)[r,n]
// (dA * h0 == 0, so A is unused.)

#define ROWS 4096
#define KDIM 1024
// GEMM tile: 128x64, BK=32 -> 512 blocks, XCD-swizzled
#define BM 128
#define BN 64
#define BK 32

typedef __attribute__((ext_vector_type(8))) __bf16 bf16x8;
typedef __attribute__((ext_vector_type(4))) float f32x4;

// ---------- helpers ----------
__device__ __forceinline__ unsigned short f2bf_rne(float f) {
    unsigned u = __float_as_uint(f);
    u += 0x7FFFu + ((u >> 16) & 1u);   // round-to-nearest-even
    return (unsigned short)(u >> 16);
}
__device__ __forceinline__ unsigned pack2(float lo, float hi) {
    return (unsigned)f2bf_rne(lo) | ((unsigned)f2bf_rne(hi) << 16);
}
__device__ __forceinline__ void async16(const void* g, void* l) {
    __builtin_amdgcn_global_load_lds(
        (const __attribute__((address_space(1))) void*)g,
        (__attribute__((address_space(3))) void*)l, 16, 0, 0);
}

// ---------- kernel 1: pure streaming fp32 -> bf16 (x, W1, W2, W3) ----------
// 2576 blocks x 256 thr x 8 elems = 5,275,648 elements exactly.
__global__ __launch_bounds__(256) void prep_kernel(
        const float* __restrict__ x,  const float* __restrict__ W1,
        const float* __restrict__ W2, const float* __restrict__ W3,
        unsigned short* __restrict__ xb, unsigned short* __restrict__ w1b,
        unsigned short* __restrict__ w2b, unsigned short* __restrict__ w3b) {
    const long long NX  = (long long)ROWS * KDIM;   // 4,194,304
    const long long NW1 = (long long)KDIM * KDIM;   // 1,048,576
    const long long NW  = 16LL * KDIM;              // 16,384
    long long i = ((long long)blockIdx.x * 256 + threadIdx.x) * 8;
    const float* src;
    unsigned short* dst;
    if (i < NX)                 { src = x  + i;                 dst = xb  + i; }
    else if (i < NX + NW1)      { src = W1 + (i - NX);          dst = w1b + (i - NX); }
    else if (i < NX + NW1 + NW) { src = W2 + (i - NX - NW1);    dst = w2b + (i - NX - NW1); }
    else                        { src = W3 + (i - NX - NW1 - NW); dst = w3b + (i - NX - NW1 - NW); }
    float4 a = *(const float4*)src;
    float4 b = *(const float4*)(src + 4);
    uint4 o;
    o.x = pack2(a.x, a.y); o.y = pack2(a.z, a.w);
    o.z = pack2(b.x, b.y); o.w = pack2(b.z, b.w);
    *(uint4*)dst = o;
}

// ---------- kernel 2: s[r] via MFMA over bf16 inputs ----------
// 256 blocks x 256 thr. Block b: rows [16b, 16b+16). Wave wv: K-chunk
// [wv*256, wv*256+256) -> 8 k-steps x 2 MFMA (B=x@W2^T, C=x@W3^T partials).
// Cross-wave reduce through LDS; then p=(B+b2)(C+b3), shuffle-sum over n.
__global__ __launch_bounds__(256) void s_kernel(
        const unsigned short* __restrict__ xb,
        const unsigned short* __restrict__ w2b, const float* __restrict__ b2,
        const unsigned short* __restrict__ w3b, const float* __restrict__ b3,
        float* __restrict__ s) {
    __shared__ f32x4 redB[4][64];
    __shared__ f32x4 redC[4][64];
    const int t = threadIdx.x;
    const int lane = t & 63;
    const int wv = t >> 6;
    const int m = lane & 15;              // A row-within-16 / B n index
    const int kq = (lane >> 4) * 8;       // k offset within 32-step
    const int r0 = blockIdx.x * 16;
    const int kbase = wv * 256;

    f32x4 accB = (f32x4){0.f, 0.f, 0.f, 0.f};
    f32x4 accC = (f32x4){0.f, 0.f, 0.f, 0.f};
    const unsigned short* xr  = xb  + (size_t)(r0 + m) * KDIM + kbase + kq;
    const unsigned short* w2r = w2b + (size_t)m * KDIM + kbase + kq;
    const unsigned short* w3r = w3b + (size_t)m * KDIM + kbase + kq;
#pragma unroll
    for (int ks = 0; ks < 256; ks += 32) {
        bf16x8 af  = *(const bf16x8*)(xr  + ks);
        bf16x8 b2f = *(const bf16x8*)(w2r + ks);
        bf16x8 b3f = *(const bf16x8*)(w3r + ks);
        accB = __builtin_amdgcn_mfma_f32_16x16x32_bf16(af, b2f, accB, 0, 0, 0);
        accC = __builtin_amdgcn_mfma_f32_16x16x32_bf16(af, b3f, accC, 0, 0, 0);
    }
    redB[wv][lane] = accB;
    redC[wv][lane] = accC;
    __syncthreads();
    if (wv == 0) {
        f32x4 tB = redB[0][lane], tC = redC[0][lane];
#pragma unroll
        for (int w = 1; w < 4; ++w) { tB += redB[w][lane]; tC += redC[w][lane]; }
        // C/D layout: lane holds D[row=(lane>>4)*4+r][col = n = lane&15]
        const float b2n = b2[m], b3n = b3[m];
        const int q4 = (lane >> 4) * 4;
#pragma unroll
        for (int r = 0; r < 4; ++r) {
            float p = (tB[r] + b2n) * (tC[r] + b3n);
            p += __shfl_xor(p, 1, 64);
            p += __shfl_xor(p, 2, 64);
            p += __shfl_xor(p, 4, 64);
            p += __shfl_xor(p, 8, 64);
            if (m == 0) s[r0 + q4 + r] = p;
        }
    }
}

// ---------- kernel 3: bf16 MFMA GEMM + fused epilogue, XCD-swizzled grid ----------
// 512 blocks (1-D). bid&7 = XCD; each XCD: 4 row-strips x 16 col-tiles ->
// per-XCD L2 working set = xb 1 MB + w1b 2 MB = 3 MB < 4 MB.
// 256 thr = 4 waves in 2x2; each wave: 64x32 via 4x2 mfma_f32_16x16x32_bf16.
__global__ __launch_bounds__(256) void gemm_fused(
        const unsigned short* __restrict__ xb,   // [4096][1024] bf16
        const unsigned short* __restrict__ w1b,  // [1024][1024] bf16 (row e, col k)
        const float* __restrict__ b1,
        const float* __restrict__ x,             // fp32 original
        const float* __restrict__ s,
        float* __restrict__ y) {
    __shared__ __align__(16) unsigned short As[BM * BK];  // 8 KB, [row][k]
    __shared__ __align__(16) unsigned short Bs[BN * BK];  // 4 KB, [col][k]

    const int bid = blockIdx.x;
    const int xcd = bid & 7;
    const int l = bid >> 3;                   // 0..63
    const int row0 = (xcd * 4 + (l >> 4)) * BM;
    const int col0 = (l & 15) * BN;

    const int t = threadIdx.x;
    const int lane = t & 63;
    const int wv = t >> 6;          // 0..3
    const int wm = wv >> 1;         // wave row 0..1 (64 rows each)
    const int wn = wv & 1;          // wave col 0..1 (32 cols each)

    f32x4 acc[4][2];
#pragma unroll
    for (int mi = 0; mi < 4; ++mi)
#pragma unroll
        for (int ni = 0; ni < 2; ++ni)
            acc[mi][ni] = (f32x4){0.f, 0.f, 0.f, 0.f};

    const int srow = (lane >> 2);        // 0..15 within 16-row chunk
    const int skoff = (lane & 3) * 8;    // 0,8,16,24 elements
    const int ml = lane & 15;
    const int kq = (lane >> 4) * 8;

    for (int k0 = 0; k0 < KDIM; k0 += BK) {
        __syncthreads();
        // A: 8 chunks of 16 rows; wave wv stages chunks 2wv, 2wv+1
#pragma unroll
        for (int i = 0; i < 2; ++i) {
            int c = wv * 2 + i;
            int rrow = c * 16 + srow;
            async16(xb + (size_t)(row0 + rrow) * KDIM + k0 + skoff, &As[c * 512]);
        }
        // B: 4 chunks of 16 rows; wave wv stages chunk wv
        {
            int rrow = wv * 16 + srow;
            async16(w1b + (size_t)(col0 + rrow) * KDIM + k0 + skoff, &Bs[wv * 512]);
        }
        __syncthreads();

        bf16x8 af[4], bfr[2];
#pragma unroll
        for (int i = 0; i < 4; ++i)
            af[i]  = *(const bf16x8*)&As[(wm * 64 + i * 16 + ml) * BK + kq];
#pragma unroll
        for (int i = 0; i < 2; ++i)
            bfr[i] = *(const bf16x8*)&Bs[(wn * 32 + i * 16 + ml) * BK + kq];
#pragma unroll
        for (int mi = 0; mi < 4; ++mi)
#pragma unroll
            for (int ni = 0; ni < 2; ++ni)
                acc[mi][ni] = __builtin_amdgcn_mfma_f32_16x16x32_bf16(
                    af[mi], bfr[ni], acc[mi][ni], 0, 0, 0);
    }

    // epilogue: y = softplus(acc + b1) * x * s ; D layout: col=lane&15, row=(lane>>4)*4+reg
    const int q4 = (lane >> 4) * 4;
#pragma unroll
    for (int mi = 0; mi < 4; ++mi) {
        const int rbase = row0 + wm * 64 + mi * 16 + q4;
        float4 s4 = *(const float4*)&s[rbase];
        const float* sp4 = (const float*)&s4;
#pragma unroll
        for (int ni = 0; ni < 2; ++ni) {
            const int c = col0 + wn * 32 + ni * 16 + ml;
            const float bias = b1[c];
#pragma unroll
            for (int r = 0; r < 4; ++r) {
                float z = acc[mi][ni][r] + bias;
                float sp = fmaxf(z, 0.f) + log1pf(__expf(-fabsf(z)));
                size_t idx = (size_t)(rbase + r) * KDIM + c;
                y[idx] = sp * x[idx] * sp4[r];
            }
        }
    }
}

// ---------- launch ----------
extern "C" void kernel_launch(void* const* d_in, const int* in_sizes, int n_in,
                              void* d_out, int out_size, void* d_ws, size_t ws_size,
                              hipStream_t stream) {
    const float* x  = (const float*)d_in[0];
    const float* W1 = (const float*)d_in[1];
    const float* b1 = (const float*)d_in[2];
    const float* W2 = (const float*)d_in[3];
    const float* b2 = (const float*)d_in[4];
    const float* W3 = (const float*)d_in[5];
    const float* b3 = (const float*)d_in[6];
    // d_in[7] = A : unused (multiplied by h0 == 0 in the reference)
    float* y = (float*)d_out;

    unsigned short* xb  = (unsigned short*)d_ws;              // 4096*1024 bf16 = 8 MB
    unsigned short* w1b = xb  + (size_t)ROWS * KDIM;          // 1024*1024 bf16 = 2 MB
    unsigned short* w2b = w1b + (size_t)KDIM * KDIM;          // 16*1024 bf16 = 32 KB
    unsigned short* w3b = w2b + (size_t)16 * KDIM;            // 16*1024 bf16 = 32 KB
    float* s = (float*)(w3b + (size_t)16 * KDIM);             // 4096 f32

    prep_kernel<<<dim3(2576), dim3(256), 0, stream>>>(x, W1, W2, W3, xb, w1b, w2b, w3b);
    s_kernel<<<dim3(256), dim3(256), 0, stream>>>(xb, w2b, b2, w3b, b3, s);
    gemm_fused<<<dim3(512), dim3(256), 0, stream>>>(xb, w1b, b1, x, s, y);
}